// Round 2
// baseline (9202.441 us; speedup 1.0000x reference)
//
#include <hip/hip_runtime.h>
#include <hip/hip_bf16.h>

// Problem constants
#define B 4
#define S 2048
#define E 1024
#define H 16
#define D 64
#define M_ROWS (B * S)   // 8192
#define HD (H * D)       // 1024

typedef __attribute__((ext_vector_type(8))) short bf16x8;   // 8 bf16 = 4 VGPRs
typedef __attribute__((ext_vector_type(4))) float f32x4;

// ---------------------------------------------------------------------------
// LayerNorm: one block (256 threads) per row of E=1024, bf16 output
// ---------------------------------------------------------------------------
__global__ void ln_kernel(const float* __restrict__ x,
                          const float* __restrict__ gamma,
                          const float* __restrict__ beta,
                          __hip_bfloat16* __restrict__ xn) {
    const int row = blockIdx.x;
    const float* xr = x + (size_t)row * E;
    __hip_bfloat16* yr = xn + (size_t)row * E;

    float vals[4];
    float sum = 0.f, sumsq = 0.f;
#pragma unroll
    for (int t = 0; t < 4; ++t) {
        float v = xr[threadIdx.x + t * 256];
        vals[t] = v;
        sum += v;
        sumsq += v * v;
    }
#pragma unroll
    for (int o = 32; o > 0; o >>= 1) {
        sum += __shfl_down(sum, o);
        sumsq += __shfl_down(sumsq, o);
    }
    __shared__ float s1[4], s2[4];
    const int wid = threadIdx.x >> 6, lane = threadIdx.x & 63;
    if (lane == 0) { s1[wid] = sum; s2[wid] = sumsq; }
    __syncthreads();
    if (threadIdx.x == 0) {
        float a = s1[0] + s1[1] + s1[2] + s1[3];
        float b2 = s2[0] + s2[1] + s2[2] + s2[3];
        float mu = a / (float)E;
        float var = b2 / (float)E - mu * mu;
        s1[0] = mu;
        s2[0] = rsqrtf(var + 1e-5f);
    }
    __syncthreads();
    const float mu = s1[0], rstd = s2[0];
#pragma unroll
    for (int t = 0; t < 4; ++t) {
        int c = threadIdx.x + t * 256;
        yr[c] = __float2bfloat16((vals[t] - mu) * rstd * gamma[c] + beta[c]);
    }
}

// ---------------------------------------------------------------------------
// Transpose fp32 W[K,N] -> bf16 Wt[N,K]  (LDS-tiled, coalesced both sides)
// grid (N/64, K/64), 256 threads
// ---------------------------------------------------------------------------
__global__ void transpose_to_bf16(const float* __restrict__ W,
                                  __hip_bfloat16* __restrict__ Wt,
                                  int K, int N) {
    __shared__ float t[64][65];
    const int n0 = blockIdx.x * 64, k0 = blockIdx.y * 64;
    const int tx = threadIdx.x & 63, ty = threadIdx.x >> 6;
#pragma unroll
    for (int i = ty; i < 64; i += 4)
        t[i][tx] = W[(size_t)(k0 + i) * N + n0 + tx];
    __syncthreads();
#pragma unroll
    for (int i = ty; i < 64; i += 4)
        Wt[(size_t)(n0 + i) * K + k0 + tx] = __float2bfloat16(t[tx][i]);
}

// ---------------------------------------------------------------------------
// bf16 MFMA GEMM: C[M,N] = A[M,K] @ Bt[N,K]^T + bias  (+ residual, fp32 out)
// 128x128 tile, BK=32, 256 threads (4 waves), each wave 64x64 (4x4 mfma tiles)
// A-frag: lane holds A[l&15][(l>>4)*8 + j]; B-frag: Bt[col=l&15][same k] —
// same k-map for A and B => correct under any HW k-permutation.
// C/D layout (HW-verified): col=lane&15, row=(lane>>4)*4+reg.
// ---------------------------------------------------------------------------
template<bool BF16OUT>
__global__ __launch_bounds__(256)
void gemm_mfma(const __hip_bfloat16* __restrict__ A,
               const __hip_bfloat16* __restrict__ Bt,
               const float* __restrict__ bias,
               const float* __restrict__ residual,
               void* __restrict__ Cout,
               int Mdim, int Ndim, int Kdim) {
    __shared__ __align__(16) short sA[128 * 32];
    __shared__ __align__(16) short sB[128 * 32];

    const int tid = threadIdx.x;
    const int lane = tid & 63;
    const int wv = tid >> 6;
    const int wr = wv >> 1, wc = wv & 1;     // wave -> 64x64 quadrant
    const int fr = lane & 15;                // fragment row/col index
    const int kg = (lane >> 4) * 8;          // fragment k offset (0,8,16,24)
    const int brow = blockIdx.y * 128;
    const int bcol = blockIdx.x * 128;

    // staging: thread t covers 16B chunks {t, 256+t}; chunk c -> row c>>2, k-sub (c&3)*8
    const int r0 = tid >> 2;
    const int sub = (tid & 3) * 8;
    const __hip_bfloat16* gA0 = A + (size_t)(brow + r0) * Kdim + sub;
    const __hip_bfloat16* gA1 = gA0 + (size_t)64 * Kdim;
    const __hip_bfloat16* gB0 = Bt + (size_t)(bcol + r0) * Kdim + sub;
    const __hip_bfloat16* gB1 = gB0 + (size_t)64 * Kdim;

    f32x4 acc[4][4] = {};

    // prefetch k0 = 0
    f32x4 pa0 = *(const f32x4*)(gA0);
    f32x4 pa1 = *(const f32x4*)(gA1);
    f32x4 pb0 = *(const f32x4*)(gB0);
    f32x4 pb1 = *(const f32x4*)(gB1);

    for (int k0 = 0; k0 < Kdim; k0 += 32) {
        ((f32x4*)sA)[tid] = pa0;
        ((f32x4*)sA)[256 + tid] = pa1;
        ((f32x4*)sB)[tid] = pb0;
        ((f32x4*)sB)[256 + tid] = pb1;
        __syncthreads();
        if (k0 + 32 < Kdim) {   // prefetch next K-slice (overlaps MFMA below)
            pa0 = *(const f32x4*)(gA0 + k0 + 32);
            pa1 = *(const f32x4*)(gA1 + k0 + 32);
            pb0 = *(const f32x4*)(gB0 + k0 + 32);
            pb1 = *(const f32x4*)(gB1 + k0 + 32);
        }
        bf16x8 af[4], bf[4];
#pragma unroll
        for (int mi = 0; mi < 4; ++mi)
            af[mi] = *(const bf16x8*)&sA[(wr * 64 + mi * 16 + fr) * 32 + kg];
#pragma unroll
        for (int ni = 0; ni < 4; ++ni)
            bf[ni] = *(const bf16x8*)&sB[(wc * 64 + ni * 16 + fr) * 32 + kg];
#pragma unroll
        for (int mi = 0; mi < 4; ++mi)
#pragma unroll
            for (int ni = 0; ni < 4; ++ni)
                acc[mi][ni] = __builtin_amdgcn_mfma_f32_16x16x32_bf16(
                    af[mi], bf[ni], acc[mi][ni], 0, 0, 0);
        __syncthreads();
    }

    // epilogue
#pragma unroll
    for (int mi = 0; mi < 4; ++mi) {
        const int rbase = brow + wr * 64 + mi * 16 + ((lane >> 4) << 2);
#pragma unroll
        for (int ni = 0; ni < 4; ++ni) {
            const int c = bcol + wc * 64 + ni * 16 + fr;
            const float bv = bias[c];
#pragma unroll
            for (int q = 0; q < 4; ++q) {
                const size_t idx = (size_t)(rbase + q) * Ndim + c;
                float v = acc[mi][ni][q] + bv;
                if constexpr (BF16OUT) {
                    ((__hip_bfloat16*)Cout)[idx] = __float2bfloat16(v);
                } else {
                    ((float*)Cout)[idx] = v + residual[idx];
                }
            }
        }
    }
}

// ---------------------------------------------------------------------------
// Causal attention, one 64-lane wave per (b,h,i) query row; lane = d.
// bf16 q,k,v in [B,S,H,D] (== [M, HD] GEMM layout); bf16 out [M, HD].
// ---------------------------------------------------------------------------
__global__ void attn_kernel(const __hip_bfloat16* __restrict__ q,
                            const __hip_bfloat16* __restrict__ k,
                            const __hip_bfloat16* __restrict__ v,
                            __hip_bfloat16* __restrict__ o) {
    const int gwave = blockIdx.x * 4 + (threadIdx.x >> 6);
    const int lane = threadIdx.x & 63;
    const int i = gwave & (S - 1);
    const int bh = gwave >> 11;            // b*H + h
    const int b = bh >> 4;
    const int h = bh & 15;

    const size_t base = ((size_t)b * S * H + h) * D;
    const size_t qidx = base + (size_t)i * HD + lane;

    const float qd = __bfloat162float(q[qidx]) * 0.125f;   // 1/sqrt(64)
    const __hip_bfloat16* kp = k + base + lane;
    const __hip_bfloat16* vp = v + base + lane;

    float m = -INFINITY, l = 0.f, acc = 0.f;
    for (int j = 0; j <= i; ++j) {
        float s = qd * __bfloat162float(kp[(size_t)j * HD]);
#pragma unroll
        for (int off = 32; off > 0; off >>= 1) s += __shfl_xor(s, off);
        const float mn = fmaxf(m, s);
        const float corr = __expf(m - mn);
        const float p = __expf(s - mn);
        l = l * corr + p;
        acc = acc * corr + p * __bfloat162float(vp[(size_t)j * HD]);
        m = mn;
    }
    o[qidx] = __float2bfloat16(acc / l);
}

// ---------------------------------------------------------------------------
extern "C" void kernel_launch(void* const* d_in, const int* in_sizes, int n_in,
                              void* d_out, int out_size, void* d_ws, size_t ws_size,
                              hipStream_t stream) {
    const float* x     = (const float*)d_in[0];
    const float* gamma = (const float*)d_in[1];
    const float* beta  = (const float*)d_in[2];
    const float* Wq    = (const float*)d_in[3];
    const float* bq    = (const float*)d_in[4];
    const float* Wk    = (const float*)d_in[5];
    const float* bk    = (const float*)d_in[6];
    const float* Wv    = (const float*)d_in[7];
    const float* bv    = (const float*)d_in[8];
    const float* Wo    = (const float*)d_in[9];
    const float* bo    = (const float*)d_in[10];
    float* out = (float*)d_out;

    const size_t nTok = (size_t)M_ROWS;
    __hip_bfloat16* xn  = (__hip_bfloat16*)d_ws;          // [M,E]   16 MB
    __hip_bfloat16* qb  = xn  + nTok * E;                 // [M,HD]  16 MB
    __hip_bfloat16* kb  = qb  + nTok * HD;
    __hip_bfloat16* vb  = kb  + nTok * HD;
    __hip_bfloat16* ao  = vb  + nTok * HD;                // attn out [M,HD]
    __hip_bfloat16* Wqt = ao  + nTok * HD;                // [HD,E] 2 MB each
    __hip_bfloat16* Wkt = Wqt + (size_t)E * HD;
    __hip_bfloat16* Wvt = Wkt + (size_t)E * HD;
    __hip_bfloat16* Wot = Wvt + (size_t)E * HD;

    // 0. weights -> bf16 transposed [N,K]
    dim3 tg(16, 16);
    transpose_to_bf16<<<tg, 256, 0, stream>>>(Wq, Wqt, E, HD);
    transpose_to_bf16<<<tg, 256, 0, stream>>>(Wk, Wkt, E, HD);
    transpose_to_bf16<<<tg, 256, 0, stream>>>(Wv, Wvt, E, HD);
    transpose_to_bf16<<<tg, 256, 0, stream>>>(Wo, Wot, HD, E);

    // 1. LayerNorm (bf16 out)
    ln_kernel<<<M_ROWS, 256, 0, stream>>>(x, gamma, beta, xn);

    // 2. QKV projections (bf16 out)
    dim3 gg(HD / 128, M_ROWS / 128);   // (8, 64)
    gemm_mfma<true><<<gg, 256, 0, stream>>>(xn, Wqt, bq, nullptr, qb, M_ROWS, HD, E);
    gemm_mfma<true><<<gg, 256, 0, stream>>>(xn, Wkt, bk, nullptr, kb, M_ROWS, HD, E);
    gemm_mfma<true><<<gg, 256, 0, stream>>>(xn, Wvt, bv, nullptr, vb, M_ROWS, HD, E);

    // 3. Causal attention (bf16 out, [M, HD])
    attn_kernel<<<(B * H * S) / 4, 256, 0, stream>>>(qb, kb, vb, ao);

    // 4. Output projection + bias + residual (fp32 out)
    dim3 go(E / 128, M_ROWS / 128);    // (8, 64)
    gemm_mfma<false><<<go, 256, 0, stream>>>(ao, Wot, bo, x, (void*)out, M_ROWS, E, HD);
}

// Round 4
// 529.332 us; speedup vs baseline: 17.3850x; 17.3850x over previous
//
#include <hip/hip_runtime.h>
#include <hip/hip_bf16.h>

// Problem constants
#define B 4
#define S 2048
#define E 1024
#define H 16
#define D 64
#define M_ROWS (B * S)   // 8192
#define HD (H * D)       // 1024

#define QBLK 128
#define KVBLK 64

typedef __attribute__((ext_vector_type(8))) short bf16x8;   // 8 bf16 = 4 VGPRs
typedef __attribute__((ext_vector_type(4))) float f32x4;

// ---------------------------------------------------------------------------
// LayerNorm: one block (256 threads) per row of E=1024, bf16 output
// ---------------------------------------------------------------------------
__global__ void ln_kernel(const float* __restrict__ x,
                          const float* __restrict__ gamma,
                          const float* __restrict__ beta,
                          __hip_bfloat16* __restrict__ xn) {
    const int row = blockIdx.x;
    const float* xr = x + (size_t)row * E;
    __hip_bfloat16* yr = xn + (size_t)row * E;

    float vals[4];
    float sum = 0.f, sumsq = 0.f;
#pragma unroll
    for (int t = 0; t < 4; ++t) {
        float v = xr[threadIdx.x + t * 256];
        vals[t] = v;
        sum += v;
        sumsq += v * v;
    }
#pragma unroll
    for (int o = 32; o > 0; o >>= 1) {
        sum += __shfl_down(sum, o);
        sumsq += __shfl_down(sumsq, o);
    }
    __shared__ float s1[4], s2[4];
    const int wid = threadIdx.x >> 6, lane = threadIdx.x & 63;
    if (lane == 0) { s1[wid] = sum; s2[wid] = sumsq; }
    __syncthreads();
    if (threadIdx.x == 0) {
        float a = s1[0] + s1[1] + s1[2] + s1[3];
        float b2 = s2[0] + s2[1] + s2[2] + s2[3];
        float mu = a / (float)E;
        float var = b2 / (float)E - mu * mu;
        s1[0] = mu;
        s2[0] = rsqrtf(var + 1e-5f);
    }
    __syncthreads();
    const float mu = s1[0], rstd = s2[0];
#pragma unroll
    for (int t = 0; t < 4; ++t) {
        int c = threadIdx.x + t * 256;
        yr[c] = __float2bfloat16((vals[t] - mu) * rstd * gamma[c] + beta[c]);
    }
}

// ---------------------------------------------------------------------------
// Transpose fp32 W[K,N] -> bf16 Wt[N,K]  (LDS-tiled, coalesced both sides)
// ---------------------------------------------------------------------------
__global__ void transpose_to_bf16(const float* __restrict__ W,
                                  __hip_bfloat16* __restrict__ Wt,
                                  int K, int N) {
    __shared__ float t[64][65];
    const int n0 = blockIdx.x * 64, k0 = blockIdx.y * 64;
    const int tx = threadIdx.x & 63, ty = threadIdx.x >> 6;
#pragma unroll
    for (int i = ty; i < 64; i += 4)
        t[i][tx] = W[(size_t)(k0 + i) * N + n0 + tx];
    __syncthreads();
#pragma unroll
    for (int i = ty; i < 64; i += 4)
        Wt[(size_t)(n0 + i) * K + k0 + tx] = __float2bfloat16(t[tx][i]);
}

// ---------------------------------------------------------------------------
// bf16 MFMA GEMM: C[M,N] = A[M,K] @ Bt[N,K]^T + bias  (+ residual, fp32 out)
// 128x128 tile, BK=32, 256 threads (4 waves), each wave 64x64 (4x4 mfma tiles)
// ---------------------------------------------------------------------------
template<bool BF16OUT>
__global__ __launch_bounds__(256)
void gemm_mfma(const __hip_bfloat16* __restrict__ A,
               const __hip_bfloat16* __restrict__ Bt,
               const float* __restrict__ bias,
               const float* __restrict__ residual,
               void* __restrict__ Cout,
               int Mdim, int Ndim, int Kdim) {
    __shared__ __align__(16) short sA[128 * 32];
    __shared__ __align__(16) short sB[128 * 32];

    const int tid = threadIdx.x;
    const int lane = tid & 63;
    const int wv = tid >> 6;
    const int wr = wv >> 1, wc = wv & 1;
    const int fr = lane & 15;
    const int kg = (lane >> 4) * 8;
    const int brow = blockIdx.y * 128;
    const int bcol = blockIdx.x * 128;

    const int r0 = tid >> 2;
    const int sub = (tid & 3) * 8;
    const __hip_bfloat16* gA0 = A + (size_t)(brow + r0) * Kdim + sub;
    const __hip_bfloat16* gA1 = gA0 + (size_t)64 * Kdim;
    const __hip_bfloat16* gB0 = Bt + (size_t)(bcol + r0) * Kdim + sub;
    const __hip_bfloat16* gB1 = gB0 + (size_t)64 * Kdim;

    f32x4 acc[4][4] = {};

    f32x4 pa0 = *(const f32x4*)(gA0);
    f32x4 pa1 = *(const f32x4*)(gA1);
    f32x4 pb0 = *(const f32x4*)(gB0);
    f32x4 pb1 = *(const f32x4*)(gB1);

    for (int k0 = 0; k0 < Kdim; k0 += 32) {
        ((f32x4*)sA)[tid] = pa0;
        ((f32x4*)sA)[256 + tid] = pa1;
        ((f32x4*)sB)[tid] = pb0;
        ((f32x4*)sB)[256 + tid] = pb1;
        __syncthreads();
        if (k0 + 32 < Kdim) {
            pa0 = *(const f32x4*)(gA0 + k0 + 32);
            pa1 = *(const f32x4*)(gA1 + k0 + 32);
            pb0 = *(const f32x4*)(gB0 + k0 + 32);
            pb1 = *(const f32x4*)(gB1 + k0 + 32);
        }
        bf16x8 af[4], bfr[4];
#pragma unroll
        for (int mi = 0; mi < 4; ++mi)
            af[mi] = *(const bf16x8*)&sA[(wr * 64 + mi * 16 + fr) * 32 + kg];
#pragma unroll
        for (int ni = 0; ni < 4; ++ni)
            bfr[ni] = *(const bf16x8*)&sB[(wc * 64 + ni * 16 + fr) * 32 + kg];
#pragma unroll
        for (int mi = 0; mi < 4; ++mi)
#pragma unroll
            for (int ni = 0; ni < 4; ++ni)
                acc[mi][ni] = __builtin_amdgcn_mfma_f32_16x16x32_bf16(
                    af[mi], bfr[ni], acc[mi][ni], 0, 0, 0);
        __syncthreads();
    }

#pragma unroll
    for (int mi = 0; mi < 4; ++mi) {
        const int rbase = brow + wr * 64 + mi * 16 + ((lane >> 4) << 2);
#pragma unroll
        for (int ni = 0; ni < 4; ++ni) {
            const int c = bcol + wc * 64 + ni * 16 + fr;
            const float bv = bias[c];
#pragma unroll
            for (int qd = 0; qd < 4; ++qd) {
                const size_t idx = (size_t)(rbase + qd) * Ndim + c;
                float v = acc[mi][ni][qd] + bv;
                if constexpr (BF16OUT) {
                    ((__hip_bfloat16*)Cout)[idx] = __float2bfloat16(v);
                } else {
                    ((float*)Cout)[idx] = v + residual[idx];
                }
            }
        }
    }
}

// ---------------------------------------------------------------------------
// MFMA flash attention, causal. Block = (b,h) x 128-row Q tile, 4 waves.
// Each wave owns 32 q rows. KV tiles of 64 staged in LDS (K swizzled,
// V transposed+swizzled). Softmax in-register on MFMA C-layout; P goes
// through wave-private padded LDS to become the PV A-operand.
// q,k,v,o layout: [B,S,H,D] == token-major [M, HD].
// ---------------------------------------------------------------------------
__global__ __launch_bounds__(256)
void flash_attn(const __hip_bfloat16* __restrict__ qg,
                const __hip_bfloat16* __restrict__ kg,
                const __hip_bfloat16* __restrict__ vg,
                __hip_bfloat16* __restrict__ og) {
    __shared__ __align__(16) short sK[KVBLK * 64];       // swizzled 16B slots
    __shared__ __align__(16) short sVt[64 * KVBLK];      // [d][kv], swizzled
    __shared__ __align__(16) short sP[4][32 * 72];       // per-wave, padded

    const int tid = threadIdx.x;
    const int lane = tid & 63;
    const int wv = tid >> 6;
    const int fr = lane & 15;     // fragment row/col (m or n index)
    const int g = lane >> 4;      // k-group

    const int nq = S / QBLK;                         // 16
    const int bq = (nq - 1) - (int)(blockIdx.x & (nq - 1));  // heavy tiles first
    const int bh = blockIdx.x / nq;
    const int b = bh >> 4, h = bh & 15;
    const int q0 = bq * QBLK;

    const size_t rowBase = ((size_t)b * S) * HD + h * D;

    // Q fragments (scaled by 1/sqrt(D) = 0.125)
    bf16x8 qa[2][2];
#pragma unroll
    for (int mt = 0; mt < 2; ++mt)
#pragma unroll
        for (int c = 0; c < 2; ++c) {
            bf16x8 t = *(const bf16x8*)&qg[rowBase + (size_t)(q0 + wv * 32 + mt * 16 + fr) * HD + c * 32 + g * 8];
            bf16x8 r;
#pragma unroll
            for (int j = 0; j < 8; ++j) {
                short sb = t[j];
                __hip_bfloat16 hb = *(__hip_bfloat16*)&sb;
                float f = __bfloat162float(hb) * 0.125f;
                __hip_bfloat16 ob = __float2bfloat16(f);
                r[j] = *(short*)&ob;
            }
            qa[mt][c] = r;
        }

    f32x4 Oacc[2][4] = {};
    float mrun[2][4], lrun[2][4];
#pragma unroll
    for (int mt = 0; mt < 2; ++mt)
#pragma unroll
        for (int r = 0; r < 4; ++r) { mrun[mt][r] = -1e30f; lrun[mt][r] = 0.f; }

    const int kvmax = (q0 + QBLK - 1) / KVBLK;   // inclusive
    for (int kvt = 0; kvt <= kvmax; ++kvt) {
        const int kv0 = kvt * KVBLK;
        __syncthreads();   // previous tile's LDS reads done
        // stage K: 2 x 16B per thread, XOR-swizzled 16B slots
#pragma unroll
        for (int it = 0; it < 2; ++it) {
            const int cc = tid + it * 256;
            const int row = cc >> 3, slot = cc & 7;
            *(bf16x8*)&sK[row * 64 + ((slot ^ (row & 7)) * 8)] =
                *(const bf16x8*)&kg[rowBase + (size_t)(kv0 + row) * HD + slot * 8];
        }
        // stage V transposed: [d][kv], swizzled
#pragma unroll
        for (int it = 0; it < 2; ++it) {
            const int kvr = (tid >> 3) + it * 32;
            const int d0 = (tid & 7) * 8;
            bf16x8 vv = *(const bf16x8*)&vg[rowBase + (size_t)(kv0 + kvr) * HD + d0];
#pragma unroll
            for (int j = 0; j < 8; ++j) {
                const int d = d0 + j;
                sVt[d * 64 + (((kvr >> 3) ^ (d & 7)) * 8) + (kvr & 7)] = vv[j];
            }
        }
        __syncthreads();

        // QK^T: S[32q x 64kv] per wave
        f32x4 sf[2][4] = {};
#pragma unroll
        for (int nt = 0; nt < 4; ++nt) {
            const int krow = nt * 16 + fr;
#pragma unroll
            for (int c = 0; c < 2; ++c) {
                bf16x8 kb = *(const bf16x8*)&sK[krow * 64 + (((c * 4 + g) ^ (krow & 7)) * 8)];
#pragma unroll
                for (int mt = 0; mt < 2; ++mt)
                    sf[mt][nt] = __builtin_amdgcn_mfma_f32_16x16x32_bf16(qa[mt][c], kb, sf[mt][nt], 0, 0, 0);
            }
        }

        // mask + online softmax + P write
#pragma unroll
        for (int mt = 0; mt < 2; ++mt) {
            const int qrow0 = q0 + wv * 32 + mt * 16 + g * 4;   // + r
            if (kv0 + KVBLK - 1 > qrow0) {
#pragma unroll
                for (int nt = 0; nt < 4; ++nt)
#pragma unroll
                    for (int r = 0; r < 4; ++r)
                        if (kv0 + nt * 16 + fr > qrow0 + r) sf[mt][nt][r] = -1e30f;
            }
#pragma unroll
            for (int r = 0; r < 4; ++r) {
                float mx = fmaxf(fmaxf(sf[mt][0][r], sf[mt][1][r]),
                                 fmaxf(sf[mt][2][r], sf[mt][3][r]));
#pragma unroll
                for (int off = 1; off < 16; off <<= 1) mx = fmaxf(mx, __shfl_xor(mx, off));
                const float mnew = fmaxf(mrun[mt][r], mx);
                const float corr = __expf(mrun[mt][r] - mnew);
                mrun[mt][r] = mnew;
                float rs = 0.f;
#pragma unroll
                for (int nt = 0; nt < 4; ++nt) {
                    float p = __expf(sf[mt][nt][r] - mnew);
                    sf[mt][nt][r] = p;
                    rs += p;
                }
#pragma unroll
                for (int off = 1; off < 16; off <<= 1) rs += __shfl_xor(rs, off);
                lrun[mt][r] = lrun[mt][r] * corr + rs;
#pragma unroll
                for (int nt2 = 0; nt2 < 4; ++nt2) Oacc[mt][nt2][r] *= corr;
            }
#pragma unroll
            for (int nt = 0; nt < 4; ++nt)
#pragma unroll
                for (int r = 0; r < 4; ++r) {
                    __hip_bfloat16 pb = __float2bfloat16(sf[mt][nt][r]);
                    sP[wv][(mt * 16 + g * 4 + r) * 72 + nt * 16 + fr] = *(short*)&pb;
                }
        }

        // PV: O += P @ V   (wave-private sP; in-wave LDS ordering)
#pragma unroll
        for (int cp = 0; cp < 2; ++cp) {
            bf16x8 pa[2];
#pragma unroll
            for (int mt = 0; mt < 2; ++mt)
                pa[mt] = *(const bf16x8*)&sP[wv][(mt * 16 + fr) * 72 + cp * 32 + g * 8];
#pragma unroll
            for (int nt = 0; nt < 4; ++nt) {
                const int vrow = nt * 16 + fr;
                bf16x8 vb = *(const bf16x8*)&sVt[vrow * 64 + (((cp * 4 + g) ^ (vrow & 7)) * 8)];
#pragma unroll
                for (int mt = 0; mt < 2; ++mt)
                    Oacc[mt][nt] = __builtin_amdgcn_mfma_f32_16x16x32_bf16(pa[mt], vb, Oacc[mt][nt], 0, 0, 0);
            }
        }
    }

    // epilogue: O / l -> bf16
#pragma unroll
    for (int mt = 0; mt < 2; ++mt) {
        float rl[4];
#pragma unroll
        for (int r = 0; r < 4; ++r) rl[r] = 1.f / lrun[mt][r];
#pragma unroll
        for (int nt = 0; nt < 4; ++nt) {
            const int d = nt * 16 + fr;
#pragma unroll
            for (int r = 0; r < 4; ++r) {
                const int qrow = q0 + wv * 32 + mt * 16 + g * 4 + r;
                og[rowBase + (size_t)qrow * HD + d] = __float2bfloat16(Oacc[mt][nt][r] * rl[r]);
            }
        }
    }
}

// ---------------------------------------------------------------------------
extern "C" void kernel_launch(void* const* d_in, const int* in_sizes, int n_in,
                              void* d_out, int out_size, void* d_ws, size_t ws_size,
                              hipStream_t stream) {
    const float* x     = (const float*)d_in[0];
    const float* gamma = (const float*)d_in[1];
    const float* beta  = (const float*)d_in[2];
    const float* Wq    = (const float*)d_in[3];
    const float* bq    = (const float*)d_in[4];
    const float* Wk    = (const float*)d_in[5];
    const float* bk    = (const float*)d_in[6];
    const float* Wv    = (const float*)d_in[7];
    const float* bv    = (const float*)d_in[8];
    const float* Wo    = (const float*)d_in[9];
    const float* bo    = (const float*)d_in[10];
    float* out = (float*)d_out;

    const size_t nTok = (size_t)M_ROWS;
    __hip_bfloat16* xn  = (__hip_bfloat16*)d_ws;          // [M,E]
    __hip_bfloat16* qb  = xn  + nTok * E;
    __hip_bfloat16* kb  = qb  + nTok * HD;
    __hip_bfloat16* vb  = kb  + nTok * HD;
    __hip_bfloat16* ao  = vb  + nTok * HD;
    __hip_bfloat16* Wqt = ao  + nTok * HD;
    __hip_bfloat16* Wkt = Wqt + (size_t)E * HD;
    __hip_bfloat16* Wvt = Wkt + (size_t)E * HD;
    __hip_bfloat16* Wot = Wvt + (size_t)E * HD;

    dim3 tg(16, 16);
    transpose_to_bf16<<<tg, 256, 0, stream>>>(Wq, Wqt, E, HD);
    transpose_to_bf16<<<tg, 256, 0, stream>>>(Wk, Wkt, E, HD);
    transpose_to_bf16<<<tg, 256, 0, stream>>>(Wv, Wvt, E, HD);
    transpose_to_bf16<<<tg, 256, 0, stream>>>(Wo, Wot, HD, E);

    ln_kernel<<<M_ROWS, 256, 0, stream>>>(x, gamma, beta, xn);

    dim3 gg(HD / 128, M_ROWS / 128);
    gemm_mfma<true><<<gg, 256, 0, stream>>>(xn, Wqt, bq, nullptr, qb, M_ROWS, HD, E);
    gemm_mfma<true><<<gg, 256, 0, stream>>>(xn, Wkt, bk, nullptr, kb, M_ROWS, HD, E);
    gemm_mfma<true><<<gg, 256, 0, stream>>>(xn, Wvt, bv, nullptr, vb, M_ROWS, HD, E);

    // MFMA flash attention
    flash_attn<<<dim3(B * H * (S / QBLK)), 256, 0, stream>>>(qb, kb, vb, ao);

    dim3 go(E / 128, M_ROWS / 128);
    gemm_mfma<false><<<go, 256, 0, stream>>>(ao, Wot, bo, x, (void*)out, M_ROWS, E, HD);
}

// Round 5
// 466.313 us; speedup vs baseline: 19.7345x; 1.1351x over previous
//
#include <hip/hip_runtime.h>
#include <hip/hip_bf16.h>

// Problem constants
#define B 4
#define S 2048
#define E 1024
#define H 16
#define D 64
#define M_ROWS (B * S)   // 8192
#define HD (H * D)       // 1024

#define QBLK 256
#define KVBLK 64

typedef __attribute__((ext_vector_type(8))) short bf16x8;   // 8 bf16 = 4 VGPRs
typedef __attribute__((ext_vector_type(4))) float f32x4;

typedef const __attribute__((address_space(1))) void* gas_ptr;
typedef __attribute__((address_space(3))) void* las_ptr;
#define GLD16(g, l) __builtin_amdgcn_global_load_lds((gas_ptr)(g), (las_ptr)(l), 16, 0, 0)

// ---------------------------------------------------------------------------
// LayerNorm: one block (256 threads) per row of E=1024, bf16 output
// ---------------------------------------------------------------------------
__global__ void ln_kernel(const float* __restrict__ x,
                          const float* __restrict__ gamma,
                          const float* __restrict__ beta,
                          __hip_bfloat16* __restrict__ xn) {
    const int row = blockIdx.x;
    const float* xr = x + (size_t)row * E;
    __hip_bfloat16* yr = xn + (size_t)row * E;

    float vals[4];
    float sum = 0.f, sumsq = 0.f;
#pragma unroll
    for (int t = 0; t < 4; ++t) {
        float v = xr[threadIdx.x + t * 256];
        vals[t] = v;
        sum += v;
        sumsq += v * v;
    }
#pragma unroll
    for (int o = 32; o > 0; o >>= 1) {
        sum += __shfl_down(sum, o);
        sumsq += __shfl_down(sumsq, o);
    }
    __shared__ float s1[4], s2[4];
    const int wid = threadIdx.x >> 6, lane = threadIdx.x & 63;
    if (lane == 0) { s1[wid] = sum; s2[wid] = sumsq; }
    __syncthreads();
    if (threadIdx.x == 0) {
        float a = s1[0] + s1[1] + s1[2] + s1[3];
        float b2 = s2[0] + s2[1] + s2[2] + s2[3];
        float mu = a / (float)E;
        float var = b2 / (float)E - mu * mu;
        s1[0] = mu;
        s2[0] = rsqrtf(var + 1e-5f);
    }
    __syncthreads();
    const float mu = s1[0], rstd = s2[0];
#pragma unroll
    for (int t = 0; t < 4; ++t) {
        int c = threadIdx.x + t * 256;
        yr[c] = __float2bfloat16((vals[t] - mu) * rstd * gamma[c] + beta[c]);
    }
}

// ---------------------------------------------------------------------------
// Transpose fp32 W[K,N] -> bf16 Wt[N,K]  (LDS-tiled, coalesced both sides)
// ---------------------------------------------------------------------------
__global__ void transpose_to_bf16(const float* __restrict__ W,
                                  __hip_bfloat16* __restrict__ Wt,
                                  int K, int N) {
    __shared__ float t[64][65];
    const int n0 = blockIdx.x * 64, k0 = blockIdx.y * 64;
    const int tx = threadIdx.x & 63, ty = threadIdx.x >> 6;
#pragma unroll
    for (int i = ty; i < 64; i += 4)
        t[i][tx] = W[(size_t)(k0 + i) * N + n0 + tx];
    __syncthreads();
#pragma unroll
    for (int i = ty; i < 64; i += 4)
        Wt[(size_t)(n0 + i) * K + k0 + tx] = __float2bfloat16(t[tx][i]);
}

// ---------------------------------------------------------------------------
// bf16 MFMA GEMM: C[M,N] = A[M,K] @ Bt[N,K]^T + bias  (+ residual, fp32 out)
// 128x128 tile, BK=32, 256 threads (4 waves); global_load_lds staging (m97).
// ---------------------------------------------------------------------------
template<bool BF16OUT>
__global__ __launch_bounds__(256)
void gemm_mfma(const __hip_bfloat16* __restrict__ A,
               const __hip_bfloat16* __restrict__ Bt,
               const float* __restrict__ bias,
               const float* __restrict__ residual,
               void* __restrict__ Cout,
               int Mdim, int Ndim, int Kdim) {
    __shared__ __align__(16) short sA[128 * 32];
    __shared__ __align__(16) short sB[128 * 32];

    const int tid = threadIdx.x;
    const int lane = tid & 63;
    const int wv = tid >> 6;
    const int wr = wv >> 1, wc = wv & 1;
    const int fr = lane & 15;
    const int kg = (lane >> 4) * 8;
    const int brow = blockIdx.y * 128;
    const int bcol = blockIdx.x * 128;

    const int r0 = tid >> 2;
    const int sub = (tid & 3) * 8;
    const __hip_bfloat16* gA0 = A + (size_t)(brow + r0) * Kdim + sub;
    const __hip_bfloat16* gA1 = gA0 + (size_t)64 * Kdim;
    const __hip_bfloat16* gB0 = Bt + (size_t)(bcol + r0) * Kdim + sub;
    const __hip_bfloat16* gB1 = gB0 + (size_t)64 * Kdim;

    f32x4 acc[4][4] = {};

    for (int k0 = 0; k0 < Kdim; k0 += 32) {
        GLD16(gA0 + k0, sA + (size_t)tid * 8);
        GLD16(gA1 + k0, sA + (size_t)(256 + tid) * 8);
        GLD16(gB0 + k0, sB + (size_t)tid * 8);
        GLD16(gB1 + k0, sB + (size_t)(256 + tid) * 8);
        __syncthreads();
        bf16x8 af[4], bfr[4];
#pragma unroll
        for (int mi = 0; mi < 4; ++mi)
            af[mi] = *(const bf16x8*)&sA[(wr * 64 + mi * 16 + fr) * 32 + kg];
#pragma unroll
        for (int ni = 0; ni < 4; ++ni)
            bfr[ni] = *(const bf16x8*)&sB[(wc * 64 + ni * 16 + fr) * 32 + kg];
#pragma unroll
        for (int mi = 0; mi < 4; ++mi)
#pragma unroll
            for (int ni = 0; ni < 4; ++ni)
                acc[mi][ni] = __builtin_amdgcn_mfma_f32_16x16x32_bf16(
                    af[mi], bfr[ni], acc[mi][ni], 0, 0, 0);
        __syncthreads();
    }

#pragma unroll
    for (int mi = 0; mi < 4; ++mi) {
        const int rbase = brow + wr * 64 + mi * 16 + ((lane >> 4) << 2);
#pragma unroll
        for (int ni = 0; ni < 4; ++ni) {
            const int c = bcol + wc * 64 + ni * 16 + fr;
            const float bv = bias[c];
#pragma unroll
            for (int qd = 0; qd < 4; ++qd) {
                const size_t idx = (size_t)(rbase + qd) * Ndim + c;
                float v = acc[mi][ni][qd] + bv;
                if constexpr (BF16OUT) {
                    ((__hip_bfloat16*)Cout)[idx] = __float2bfloat16(v);
                } else {
                    ((float*)Cout)[idx] = v + residual[idx];
                }
            }
        }
    }
}

// ---------------------------------------------------------------------------
// MFMA flash attention, causal. Block = (b,h) x 256-row Q tile, 8 waves.
// Each wave owns 32 q rows. KV tiles of 64 double-buffered in LDS
// (K swizzled; V transposed via coalesced u16 loads + swizzled b128 writes).
// Register prefetch of tile t+1 overlaps tile t compute; 1 barrier/tile.
// q,k,v,o layout: [B,S,H,D] == token-major [M, HD].
// ---------------------------------------------------------------------------
__global__ __launch_bounds__(512)
void flash_attn(const __hip_bfloat16* __restrict__ qg,
                const __hip_bfloat16* __restrict__ kg,
                const __hip_bfloat16* __restrict__ vg,
                __hip_bfloat16* __restrict__ og) {
    __shared__ __align__(16) short sK[2][KVBLK * 64];    // [kv][d] swizzled 16B slots
    __shared__ __align__(16) short sVt[2][64 * KVBLK];   // [d][kv] swizzled
    __shared__ __align__(16) short sP[8][32 * 72];       // per-wave, padded

    const int tid = threadIdx.x;
    const int lane = tid & 63;
    const int wv = tid >> 6;      // 0..7
    const int fr = lane & 15;
    const int g = lane >> 4;

    const int nq = S / QBLK;                              // 8
    const int bq = (nq - 1) - (int)(blockIdx.x & (nq - 1));  // heavy tiles first
    const int bh = blockIdx.x / nq;
    const int b = bh >> 4, h = bh & 15;
    const int q0 = bq * QBLK;

    const size_t rowBase = ((size_t)b * S) * HD + h * D;
    const unsigned short* vg16 = (const unsigned short*)vg;

    // Q fragments (scaled by 1/sqrt(D) = 0.125)
    bf16x8 qa[2][2];
#pragma unroll
    for (int mt = 0; mt < 2; ++mt)
#pragma unroll
        for (int c = 0; c < 2; ++c) {
            bf16x8 t = *(const bf16x8*)&qg[rowBase + (size_t)(q0 + wv * 32 + mt * 16 + fr) * HD + c * 32 + g * 8];
            bf16x8 r;
#pragma unroll
            for (int j = 0; j < 8; ++j) {
                short sb = t[j];
                __hip_bfloat16 hb = *(__hip_bfloat16*)&sb;
                float f = __bfloat162float(hb) * 0.125f;
                __hip_bfloat16 ob = __float2bfloat16(f);
                r[j] = *(short*)&ob;
            }
            qa[mt][c] = r;
        }

    // staging indices
    const int krow = tid >> 3;        // 0..63
    const int kslot = tid & 7;        // 0..7
    const int vd = tid & 63;          // d index
    const int kvi = tid >> 6;         // 0..7 (== wv)

    f32x4 Oacc[2][4] = {};
    float mrun[2][4], lrun[2][4];
#pragma unroll
    for (int mt = 0; mt < 2; ++mt)
#pragma unroll
        for (int r = 0; r < 4; ++r) { mrun[mt][r] = -1e30f; lrun[mt][r] = 0.f; }

    const int kvmax = (q0 + QBLK - 1) / KVBLK;   // inclusive last tile
    const int qmaxw = q0 + wv * 32 + 31;         // wave's last q row

    // prologue: prefetch tile 0 into regs
    bf16x8 kpre = *(const bf16x8*)&kg[rowBase + (size_t)krow * HD + kslot * 8];
    bf16x8 vpre;
#pragma unroll
    for (int j = 0; j < 8; ++j)
        vpre[j] = (short)vg16[rowBase + (size_t)(kvi * 8 + j) * HD + vd];

    for (int kvt = 0; kvt <= kvmax; ++kvt) {
        const int kv0 = kvt * KVBLK;
        const int cur = kvt & 1;

        // write prefetched tile to LDS (b128, swizzled, conflict-optimal)
        *(bf16x8*)&sK[cur][krow * 64 + ((kslot ^ (krow & 7)) * 8)] = kpre;
        *(bf16x8*)&sVt[cur][vd * 64 + ((kvi ^ (vd & 7)) * 8)] = vpre;
        __syncthreads();

        // issue next tile's global loads (lands during this tile's compute)
        if (kvt < kvmax) {
            const int kv0n = kv0 + KVBLK;
            kpre = *(const bf16x8*)&kg[rowBase + (size_t)(kv0n + krow) * HD + kslot * 8];
#pragma unroll
            for (int j = 0; j < 8; ++j)
                vpre[j] = (short)vg16[rowBase + (size_t)(kv0n + kvi * 8 + j) * HD + vd];
        }

        if (kv0 <= qmaxw) {   // skip fully-masked tiles for this wave
            // QK^T: S[32q x 64kv] per wave
            f32x4 sf[2][4] = {};
#pragma unroll
            for (int nt = 0; nt < 4; ++nt) {
                const int kr = nt * 16 + fr;
#pragma unroll
                for (int c = 0; c < 2; ++c) {
                    bf16x8 kb = *(const bf16x8*)&sK[cur][kr * 64 + (((c * 4 + g) ^ (kr & 7)) * 8)];
#pragma unroll
                    for (int mt = 0; mt < 2; ++mt)
                        sf[mt][nt] = __builtin_amdgcn_mfma_f32_16x16x32_bf16(qa[mt][c], kb, sf[mt][nt], 0, 0, 0);
                }
            }

            // mask + online softmax + P write
#pragma unroll
            for (int mt = 0; mt < 2; ++mt) {
                const int qrow0 = q0 + wv * 32 + mt * 16 + g * 4;   // + r
                if (kv0 + KVBLK - 1 > qrow0) {
#pragma unroll
                    for (int nt = 0; nt < 4; ++nt)
#pragma unroll
                        for (int r = 0; r < 4; ++r)
                            if (kv0 + nt * 16 + fr > qrow0 + r) sf[mt][nt][r] = -1e30f;
                }
#pragma unroll
                for (int r = 0; r < 4; ++r) {
                    float mx = fmaxf(fmaxf(sf[mt][0][r], sf[mt][1][r]),
                                     fmaxf(sf[mt][2][r], sf[mt][3][r]));
#pragma unroll
                    for (int off = 1; off < 16; off <<= 1) mx = fmaxf(mx, __shfl_xor(mx, off));
                    const float mnew = fmaxf(mrun[mt][r], mx);
                    const float corr = __expf(mrun[mt][r] - mnew);
                    mrun[mt][r] = mnew;
                    float rs = 0.f;
#pragma unroll
                    for (int nt = 0; nt < 4; ++nt) {
                        float p = __expf(sf[mt][nt][r] - mnew);
                        sf[mt][nt][r] = p;
                        rs += p;
                    }
#pragma unroll
                    for (int off = 1; off < 16; off <<= 1) rs += __shfl_xor(rs, off);
                    lrun[mt][r] = lrun[mt][r] * corr + rs;
#pragma unroll
                    for (int nt2 = 0; nt2 < 4; ++nt2) Oacc[mt][nt2][r] *= corr;
                }
#pragma unroll
                for (int nt = 0; nt < 4; ++nt)
#pragma unroll
                    for (int r = 0; r < 4; ++r) {
                        __hip_bfloat16 pb = __float2bfloat16(sf[mt][nt][r]);
                        sP[wv][(mt * 16 + g * 4 + r) * 72 + nt * 16 + fr] = *(short*)&pb;
                    }
            }

            // PV: O += P @ V   (wave-private sP)
#pragma unroll
            for (int cp = 0; cp < 2; ++cp) {
                bf16x8 pa[2];
#pragma unroll
                for (int mt = 0; mt < 2; ++mt)
                    pa[mt] = *(const bf16x8*)&sP[wv][(mt * 16 + fr) * 72 + cp * 32 + g * 8];
#pragma unroll
                for (int nt = 0; nt < 4; ++nt) {
                    const int vrow = nt * 16 + fr;
                    bf16x8 vb = *(const bf16x8*)&sVt[cur][vrow * 64 + (((cp * 4 + g) ^ (vrow & 7)) * 8)];
#pragma unroll
                    for (int mt = 0; mt < 2; ++mt)
                        Oacc[mt][nt] = __builtin_amdgcn_mfma_f32_16x16x32_bf16(pa[mt], vb, Oacc[mt][nt], 0, 0, 0);
                }
            }
        }
    }

    // epilogue: O / l -> bf16
#pragma unroll
    for (int mt = 0; mt < 2; ++mt) {
        float rl[4];
#pragma unroll
        for (int r = 0; r < 4; ++r) rl[r] = 1.f / lrun[mt][r];
#pragma unroll
        for (int nt = 0; nt < 4; ++nt) {
            const int d = nt * 16 + fr;
#pragma unroll
            for (int r = 0; r < 4; ++r) {
                const int qrow = q0 + wv * 32 + mt * 16 + g * 4 + r;
                og[rowBase + (size_t)qrow * HD + d] = __float2bfloat16(Oacc[mt][nt][r] * rl[r]);
            }
        }
    }
}

// ---------------------------------------------------------------------------
extern "C" void kernel_launch(void* const* d_in, const int* in_sizes, int n_in,
                              void* d_out, int out_size, void* d_ws, size_t ws_size,
                              hipStream_t stream) {
    const float* x     = (const float*)d_in[0];
    const float* gamma = (const float*)d_in[1];
    const float* beta  = (const float*)d_in[2];
    const float* Wq    = (const float*)d_in[3];
    const float* bq    = (const float*)d_in[4];
    const float* Wk    = (const float*)d_in[5];
    const float* bk    = (const float*)d_in[6];
    const float* Wv    = (const float*)d_in[7];
    const float* bv    = (const float*)d_in[8];
    const float* Wo    = (const float*)d_in[9];
    const float* bo    = (const float*)d_in[10];
    float* out = (float*)d_out;

    const size_t nTok = (size_t)M_ROWS;
    __hip_bfloat16* xn  = (__hip_bfloat16*)d_ws;          // [M,E]
    __hip_bfloat16* qb  = xn  + nTok * E;
    __hip_bfloat16* kb  = qb  + nTok * HD;
    __hip_bfloat16* vb  = kb  + nTok * HD;
    __hip_bfloat16* ao  = vb  + nTok * HD;
    __hip_bfloat16* Wqt = ao  + nTok * HD;
    __hip_bfloat16* Wkt = Wqt + (size_t)E * HD;
    __hip_bfloat16* Wvt = Wkt + (size_t)E * HD;
    __hip_bfloat16* Wot = Wvt + (size_t)E * HD;

    dim3 tg(16, 16);
    transpose_to_bf16<<<tg, 256, 0, stream>>>(Wq, Wqt, E, HD);
    transpose_to_bf16<<<tg, 256, 0, stream>>>(Wk, Wkt, E, HD);
    transpose_to_bf16<<<tg, 256, 0, stream>>>(Wv, Wvt, E, HD);
    transpose_to_bf16<<<tg, 256, 0, stream>>>(Wo, Wot, HD, E);

    ln_kernel<<<M_ROWS, 256, 0, stream>>>(x, gamma, beta, xn);

    dim3 gg(HD / 128, M_ROWS / 128);
    gemm_mfma<true><<<gg, 256, 0, stream>>>(xn, Wqt, bq, nullptr, qb, M_ROWS, HD, E);
    gemm_mfma<true><<<gg, 256, 0, stream>>>(xn, Wkt, bk, nullptr, kb, M_ROWS, HD, E);
    gemm_mfma<true><<<gg, 256, 0, stream>>>(xn, Wvt, bv, nullptr, vb, M_ROWS, HD, E);

    // MFMA flash attention (8 waves, double-buffered KV)
    flash_attn<<<dim3(B * H * (S / QBLK)), 512, 0, stream>>>(qb, kb, vb, ao);

    dim3 go(E / 128, M_ROWS / 128);
    gemm_mfma<false><<<go, 256, 0, stream>>>(ao, Wot, bo, x, (void*)out, M_ROWS, E, HD);
}

// Round 6
// 317.690 us; speedup vs baseline: 28.9667x; 1.4678x over previous
//
#include <hip/hip_runtime.h>
#include <hip/hip_bf16.h>

// Problem constants
#define B 4
#define S 2048
#define E 1024
#define H 16
#define D 64
#define M_ROWS (B * S)   // 8192
#define HD (H * D)       // 1024
#define QKVW (3 * HD)    // 3072

#define QBLK 128
#define KVBLK 64

typedef __attribute__((ext_vector_type(8))) short bf16x8;   // 8 bf16 = 4 VGPRs
typedef __attribute__((ext_vector_type(4))) float f32x4;

typedef const __attribute__((address_space(1))) void* gas_ptr;
typedef __attribute__((address_space(3))) void* las_ptr;
#define GLD16(g, l) __builtin_amdgcn_global_load_lds((gas_ptr)(g), (las_ptr)(l), 16, 0, 0)

// ---------------------------------------------------------------------------
// LayerNorm: one block (256 threads) per row of E=1024, bf16 output
// ---------------------------------------------------------------------------
__global__ void ln_kernel(const float* __restrict__ x,
                          const float* __restrict__ gamma,
                          const float* __restrict__ beta,
                          __hip_bfloat16* __restrict__ xn) {
    const int row = blockIdx.x;
    const float* xr = x + (size_t)row * E;
    __hip_bfloat16* yr = xn + (size_t)row * E;

    float vals[4];
    float sum = 0.f, sumsq = 0.f;
#pragma unroll
    for (int t = 0; t < 4; ++t) {
        float v = xr[threadIdx.x + t * 256];
        vals[t] = v;
        sum += v;
        sumsq += v * v;
    }
#pragma unroll
    for (int o = 32; o > 0; o >>= 1) {
        sum += __shfl_down(sum, o);
        sumsq += __shfl_down(sumsq, o);
    }
    __shared__ float s1[4], s2[4];
    const int wid = threadIdx.x >> 6, lane = threadIdx.x & 63;
    if (lane == 0) { s1[wid] = sum; s2[wid] = sumsq; }
    __syncthreads();
    if (threadIdx.x == 0) {
        float a = s1[0] + s1[1] + s1[2] + s1[3];
        float b2 = s2[0] + s2[1] + s2[2] + s2[3];
        float mu = a / (float)E;
        float var = b2 / (float)E - mu * mu;
        s1[0] = mu;
        s2[0] = rsqrtf(var + 1e-5f);
    }
    __syncthreads();
    const float mu = s1[0], rstd = s2[0];
#pragma unroll
    for (int t = 0; t < 4; ++t) {
        int c = threadIdx.x + t * 256;
        yr[c] = __float2bfloat16((vals[t] - mu) * rstd * gamma[c] + beta[c]);
    }
}

// ---------------------------------------------------------------------------
// Transpose fp32 W[K,N] -> bf16 Wt[N,K]  (LDS-tiled, coalesced both sides)
// ---------------------------------------------------------------------------
__global__ void transpose_to_bf16(const float* __restrict__ W,
                                  __hip_bfloat16* __restrict__ Wt,
                                  int K, int N) {
    __shared__ float t[64][65];
    const int n0 = blockIdx.x * 64, k0 = blockIdx.y * 64;
    const int tx = threadIdx.x & 63, ty = threadIdx.x >> 6;
#pragma unroll
    for (int i = ty; i < 64; i += 4)
        t[i][tx] = W[(size_t)(k0 + i) * N + n0 + tx];
    __syncthreads();
#pragma unroll
    for (int i = ty; i < 64; i += 4)
        Wt[(size_t)(n0 + i) * K + k0 + tx] = __float2bfloat16(t[tx][i]);
}

// pack bq|bk|bv into one 3072 vector
__global__ void pack_bias(const float* __restrict__ bq, const float* __restrict__ bk,
                          const float* __restrict__ bv, float* __restrict__ o) {
    const int t = threadIdx.x;
    o[t] = bq[t]; o[HD + t] = bk[t]; o[2 * HD + t] = bv[t];
}

// ---------------------------------------------------------------------------
// bf16 MFMA GEMM: C[M,N] = A[M,K] @ Bt[N,K]^T + bias  (+ residual, fp32 out)
// 128x128 tile, BK=32, 256 threads (4 waves); global_load_lds staging (m97).
// ---------------------------------------------------------------------------
template<bool BF16OUT>
__global__ __launch_bounds__(256)
void gemm_mfma(const __hip_bfloat16* __restrict__ A,
               const __hip_bfloat16* __restrict__ Bt,
               const float* __restrict__ bias,
               const float* __restrict__ residual,
               void* __restrict__ Cout,
               int Mdim, int Ndim, int Kdim) {
    __shared__ __align__(16) short sA[128 * 32];
    __shared__ __align__(16) short sB[128 * 32];

    const int tid = threadIdx.x;
    const int lane = tid & 63;
    const int wv = tid >> 6;
    const int wr = wv >> 1, wc = wv & 1;
    const int fr = lane & 15;
    const int kg = (lane >> 4) * 8;
    const int brow = blockIdx.y * 128;
    const int bcol = blockIdx.x * 128;

    const int r0 = tid >> 2;
    const int sub = (tid & 3) * 8;
    const __hip_bfloat16* gA0 = A + (size_t)(brow + r0) * Kdim + sub;
    const __hip_bfloat16* gA1 = gA0 + (size_t)64 * Kdim;
    const __hip_bfloat16* gB0 = Bt + (size_t)(bcol + r0) * Kdim + sub;
    const __hip_bfloat16* gB1 = gB0 + (size_t)64 * Kdim;

    f32x4 acc[4][4] = {};

    for (int k0 = 0; k0 < Kdim; k0 += 32) {
        GLD16(gA0 + k0, sA + (size_t)tid * 8);
        GLD16(gA1 + k0, sA + (size_t)(256 + tid) * 8);
        GLD16(gB0 + k0, sB + (size_t)tid * 8);
        GLD16(gB1 + k0, sB + (size_t)(256 + tid) * 8);
        __syncthreads();
        bf16x8 af[4], bfr[4];
#pragma unroll
        for (int mi = 0; mi < 4; ++mi)
            af[mi] = *(const bf16x8*)&sA[(wr * 64 + mi * 16 + fr) * 32 + kg];
#pragma unroll
        for (int ni = 0; ni < 4; ++ni)
            bfr[ni] = *(const bf16x8*)&sB[(wc * 64 + ni * 16 + fr) * 32 + kg];
#pragma unroll
        for (int mi = 0; mi < 4; ++mi)
#pragma unroll
            for (int ni = 0; ni < 4; ++ni)
                acc[mi][ni] = __builtin_amdgcn_mfma_f32_16x16x32_bf16(
                    af[mi], bfr[ni], acc[mi][ni], 0, 0, 0);
        __syncthreads();
    }

#pragma unroll
    for (int mi = 0; mi < 4; ++mi) {
        const int rbase = brow + wr * 64 + mi * 16 + ((lane >> 4) << 2);
#pragma unroll
        for (int ni = 0; ni < 4; ++ni) {
            const int c = bcol + wc * 64 + ni * 16 + fr;
            const float bv = bias[c];
#pragma unroll
            for (int qd = 0; qd < 4; ++qd) {
                const size_t idx = (size_t)(rbase + qd) * Ndim + c;
                float v = acc[mi][ni][qd] + bv;
                if constexpr (BF16OUT) {
                    ((__hip_bfloat16*)Cout)[idx] = __float2bfloat16(v);
                } else {
                    ((float*)Cout)[idx] = v + residual[idx];
                }
            }
        }
    }
}

// ---------------------------------------------------------------------------
// MFMA flash attention, causal, SWAPPED QK^T (mfma(K,Q): C cols = q).
// Block = (b,h, pair p): processes q-tiles {15-p, p} (36 kv-iters, uniform).
// 4 waves x 32 q rows. KV dbuf in LDS; V transposed. Softmax in-lane.
// qkv layout: [M, 3072] (q|k|v); out: [M, 1024].
// ---------------------------------------------------------------------------
__global__ __launch_bounds__(256)
void flash_attn(const __hip_bfloat16* __restrict__ qkv,
                __hip_bfloat16* __restrict__ og) {
    __shared__ __align__(16) short sK[2][KVBLK * 64];    // [kv][d] swizzled 16B slots
    __shared__ __align__(16) short sVt[2][64 * KVBLK];   // [d][kv] swizzled
    __shared__ __align__(16) short sP[4][32 * 72];       // [q][kv] per-wave, padded

    const int tid = threadIdx.x;
    const int lane = tid & 63;
    const int wv = tid >> 6;      // 0..3
    const int fr = lane & 15;
    const int g = lane >> 4;

    const int p = blockIdx.x & 7;          // pair id
    const int bh = blockIdx.x >> 3;
    const int b = bh >> 4, h = bh & 15;

    const __hip_bfloat16* qp = qkv + (size_t)b * S * QKVW + h * D;
    const __hip_bfloat16* kp = qp + HD;
    const unsigned short* vp16 = (const unsigned short*)(qp + 2 * HD);
    const size_t ogBase = (size_t)b * S * HD + h * D;

    // staging indices
    const int krow = tid >> 3;    // 0..31 (+32 on it=1)
    const int kslot = tid & 7;

#pragma unroll
    for (int qi = 0; qi < 2; ++qi) {
        const int bq = qi ? p : (15 - p);
        const int q0 = bq * QBLK;

        // Q fragments (B-operand), scaled by 1/sqrt(D)=0.125
        bf16x8 qa[2][2];
#pragma unroll
        for (int mt = 0; mt < 2; ++mt)
#pragma unroll
            for (int c = 0; c < 2; ++c) {
                bf16x8 t = *(const bf16x8*)&qp[(size_t)(q0 + wv * 32 + mt * 16 + fr) * QKVW + c * 32 + g * 8];
                bf16x8 r;
#pragma unroll
                for (int j = 0; j < 8; ++j) {
                    short sb = t[j];
                    __hip_bfloat16 hb = *(__hip_bfloat16*)&sb;
                    float f = __bfloat162float(hb) * 0.125f;
                    __hip_bfloat16 ob = __float2bfloat16(f);
                    r[j] = *(short*)&ob;
                }
                qa[mt][c] = r;
            }

        f32x4 Oacc[2][4] = {};
        float mrun[2] = {-1e30f, -1e30f}, lrun[2] = {0.f, 0.f};

        const int kvmax = 2 * bq + 1;             // inclusive last kv tile
        const int qmaxw = q0 + wv * 32 + 31;

        __syncthreads();   // previous q-tile's LDS reads done

        // prologue: prefetch tile 0 into regs
        bf16x8 kpre[2], vpre[2];
#pragma unroll
        for (int it = 0; it < 2; ++it) {
            kpre[it] = *(const bf16x8*)&kp[(size_t)(krow + it * 32) * QKVW + kslot * 8];
#pragma unroll
            for (int j = 0; j < 8; ++j)
                vpre[it][j] = (short)vp16[(size_t)((wv + it * 4) * 8 + j) * QKVW + lane];
        }

        for (int kvt = 0; kvt <= kvmax; ++kvt) {
            const int kv0 = kvt * KVBLK;
            const int cur = kvt & 1;

            // write prefetched tile to LDS (b128 swizzled)
#pragma unroll
            for (int it = 0; it < 2; ++it) {
                const int r = krow + it * 32;
                *(bf16x8*)&sK[cur][r * 64 + ((kslot ^ (r & 7)) * 8)] = kpre[it];
                *(bf16x8*)&sVt[cur][lane * 64 + (((wv + it * 4) ^ (lane & 7)) * 8)] = vpre[it];
            }
            __syncthreads();

            // issue next tile's global loads (land during this tile's compute)
            if (kvt < kvmax) {
                const int kv0n = kv0 + KVBLK;
#pragma unroll
                for (int it = 0; it < 2; ++it) {
                    kpre[it] = *(const bf16x8*)&kp[(size_t)(kv0n + krow + it * 32) * QKVW + kslot * 8];
#pragma unroll
                    for (int j = 0; j < 8; ++j)
                        vpre[it][j] = (short)vp16[(size_t)(kv0n + (wv + it * 4) * 8 + j) * QKVW + lane];
                }
            }

            if (kv0 <= qmaxw) {   // wave skips fully-masked tiles
                // QK^T swapped: sf[mt][nt]: q=mt*16+fr (col), kv=nt*16+g*4+r (row)
                f32x4 sf[2][4] = {};
#pragma unroll
                for (int nt = 0; nt < 4; ++nt) {
                    const int kr = nt * 16 + fr;
#pragma unroll
                    for (int c = 0; c < 2; ++c) {
                        bf16x8 kb = *(const bf16x8*)&sK[cur][kr * 64 + (((c * 4 + g) ^ (kr & 7)) * 8)];
#pragma unroll
                        for (int mt = 0; mt < 2; ++mt)
                            sf[mt][nt] = __builtin_amdgcn_mfma_f32_16x16x32_bf16(kb, qa[mt][c], sf[mt][nt], 0, 0, 0);
                    }
                }

#pragma unroll
                for (int mt = 0; mt < 2; ++mt) {
                    const int qabs = q0 + wv * 32 + mt * 16 + fr;
                    // causal mask (skip if tile fully below diagonal for this mt)
                    if (kv0 + KVBLK - 1 > q0 + wv * 32 + mt * 16) {
#pragma unroll
                        for (int nt = 0; nt < 4; ++nt)
#pragma unroll
                            for (int r = 0; r < 4; ++r)
                                if (kv0 + nt * 16 + g * 4 + r > qabs) sf[mt][nt][r] = -1e30f;
                    }
                    // in-lane max over 16 + cross-g reduce
                    float mx = -1e30f;
#pragma unroll
                    for (int nt = 0; nt < 4; ++nt)
#pragma unroll
                        for (int r = 0; r < 4; ++r) mx = fmaxf(mx, sf[mt][nt][r]);
                    mx = fmaxf(mx, __shfl_xor(mx, 16));
                    mx = fmaxf(mx, __shfl_xor(mx, 32));
                    const float mnew = fmaxf(mrun[mt], mx);
                    const float corr = __expf(mrun[mt] - mnew);
                    mrun[mt] = mnew;
                    float rs = 0.f;
#pragma unroll
                    for (int nt = 0; nt < 4; ++nt)
#pragma unroll
                        for (int r = 0; r < 4; ++r) {
                            float pv = __expf(sf[mt][nt][r] - mnew);
                            sf[mt][nt][r] = pv;
                            rs += pv;
                        }
                    rs += __shfl_xor(rs, 16);
                    rs += __shfl_xor(rs, 32);
                    lrun[mt] = lrun[mt] * corr + rs;
                    // rescale Oacc rows (corr for q=mt*16+g*4+r lives in lane g*4+r)
#pragma unroll
                    for (int r = 0; r < 4; ++r) {
                        const float corrO = __shfl(corr, g * 4 + r);
#pragma unroll
                        for (int nt = 0; nt < 4; ++nt) Oacc[mt][nt][r] *= corrO;
                    }
                    // pack P (4 kv-consecutive bf16) -> b64 LDS writes
#pragma unroll
                    for (int nt = 0; nt < 4; ++nt) {
                        ushort4 pk;
#pragma unroll
                        for (int r = 0; r < 4; ++r) {
                            __hip_bfloat16 pb = __float2bfloat16(sf[mt][nt][r]);
                            ((unsigned short*)&pk)[r] = *(unsigned short*)&pb;
                        }
                        *(ushort4*)&sP[wv][(mt * 16 + fr) * 72 + nt * 16 + g * 4] = pk;
                    }
                }

                // PV: O += P @ V (wave-private sP; b128 reads)
#pragma unroll
                for (int cp = 0; cp < 2; ++cp) {
                    bf16x8 pa[2];
#pragma unroll
                    for (int mt = 0; mt < 2; ++mt)
                        pa[mt] = *(const bf16x8*)&sP[wv][(mt * 16 + fr) * 72 + cp * 32 + g * 8];
#pragma unroll
                    for (int nt = 0; nt < 4; ++nt) {
                        const int vrow = nt * 16 + fr;
                        bf16x8 vb = *(const bf16x8*)&sVt[cur][vrow * 64 + (((cp * 4 + g) ^ (vrow & 7)) * 8)];
#pragma unroll
                        for (int mt = 0; mt < 2; ++mt)
                            Oacc[mt][nt] = __builtin_amdgcn_mfma_f32_16x16x32_bf16(pa[mt], vb, Oacc[mt][nt], 0, 0, 0);
                    }
                }
            }
        }

        // epilogue: O / l -> bf16  (d=nt*16+fr, q=mt*16+g*4+r)
#pragma unroll
        for (int mt = 0; mt < 2; ++mt) {
            float rl[4];
#pragma unroll
            for (int r = 0; r < 4; ++r) rl[r] = 1.f / __shfl(lrun[mt], g * 4 + r);
#pragma unroll
            for (int nt = 0; nt < 4; ++nt) {
                const int d = nt * 16 + fr;
#pragma unroll
                for (int r = 0; r < 4; ++r) {
                    const int qrow = q0 + wv * 32 + mt * 16 + g * 4 + r;
                    og[ogBase + (size_t)qrow * HD + d] = __float2bfloat16(Oacc[mt][nt][r] * rl[r]);
                }
            }
        }
    }
}

// ---------------------------------------------------------------------------
extern "C" void kernel_launch(void* const* d_in, const int* in_sizes, int n_in,
                              void* d_out, int out_size, void* d_ws, size_t ws_size,
                              hipStream_t stream) {
    const float* x     = (const float*)d_in[0];
    const float* gamma = (const float*)d_in[1];
    const float* beta  = (const float*)d_in[2];
    const float* Wq    = (const float*)d_in[3];
    const float* bq    = (const float*)d_in[4];
    const float* Wk    = (const float*)d_in[5];
    const float* bk    = (const float*)d_in[6];
    const float* Wv    = (const float*)d_in[7];
    const float* bv    = (const float*)d_in[8];
    const float* Wo    = (const float*)d_in[9];
    const float* bo    = (const float*)d_in[10];
    float* out = (float*)d_out;

    const size_t nTok = (size_t)M_ROWS;
    __hip_bfloat16* xn    = (__hip_bfloat16*)d_ws;            // [M,E]    16 MB
    __hip_bfloat16* qkv   = xn + nTok * E;                    // [M,3072] 48 MB
    __hip_bfloat16* ao    = qkv + nTok * QKVW;                // [M,HD]   16 MB
    __hip_bfloat16* Wqkvt = ao + nTok * HD;                   // [3072,E]  6 MB
    __hip_bfloat16* Wot   = Wqkvt + (size_t)QKVW * E;         // [E,HD]    2 MB
    float* bqkv           = (float*)(Wot + (size_t)E * HD);   // [3072]

    // 0. weights -> bf16 transposed; biases packed
    dim3 tg(16, 16);
    transpose_to_bf16<<<tg, 256, 0, stream>>>(Wq, Wqkvt,                     E, HD);
    transpose_to_bf16<<<tg, 256, 0, stream>>>(Wk, Wqkvt + (size_t)HD * E,    E, HD);
    transpose_to_bf16<<<tg, 256, 0, stream>>>(Wv, Wqkvt + (size_t)2 * HD * E, E, HD);
    transpose_to_bf16<<<tg, 256, 0, stream>>>(Wo, Wot, HD, E);
    pack_bias<<<1, HD, 0, stream>>>(bq, bk, bv, bqkv);

    // 1. LayerNorm
    ln_kernel<<<M_ROWS, 256, 0, stream>>>(x, gamma, beta, xn);

    // 2. fused QKV projection [M,3072]
    dim3 gg(QKVW / 128, M_ROWS / 128);   // (24, 64)
    gemm_mfma<true><<<gg, 256, 0, stream>>>(xn, Wqkvt, bqkv, nullptr, qkv, M_ROWS, QKVW, E);

    // 3. flash attention (paired q-tiles, swapped QK^T)
    flash_attn<<<dim3(B * H * 8), 256, 0, stream>>>(qkv, ao);

    // 4. output projection + bias + residual
    dim3 go(E / 128, M_ROWS / 128);      // (8, 64)
    gemm_mfma<false><<<go, 256, 0, stream>>>(ao, Wot, bo, x, (void*)out, M_ROWS, E, HD);
}